// Round 8
// baseline (2121.534 us; speedup 1.0000x reference)
//
#include <hip/hip_runtime.h>
#include <math.h>

#define NS 4
#define NB 32
#define CIN 128
#define NCOUT 256
#define HWN 256
#define ND 1152
#define NK 8192   // NB*HWN
static const size_t D2 = (size_t)ND * ND;

typedef __attribute__((ext_vector_type(8))) short bf16x8;
typedef __attribute__((ext_vector_type(4))) float f32x4;

static __device__ inline unsigned short f2bf(float x) {
  unsigned int u = __float_as_uint(x);
  unsigned int r = (u + 0x7fffu + ((u >> 16) & 1u)) >> 16;
  return (unsigned short)r;
}
static __device__ inline float bf2f(unsigned short h) {
  return __uint_as_float(((unsigned int)h) << 16);
}
static __device__ inline float rdlane(float v, int l) {
  return __int_as_float(__builtin_amdgcn_readlane(__float_as_int(v), l));
}
// R2-proven wait/publish: ONE wave polls (one acquire = one L2 inv), barrier
// broadcasts. publish: fence (writeback) + barrier + single release store.
static __device__ __forceinline__ void waitflag0(const int* f, int tid) {
  if (tid == 0) {
    while (__hip_atomic_load(f, __ATOMIC_RELAXED, __HIP_MEMORY_SCOPE_AGENT) == 0)
      __builtin_amdgcn_s_sleep(2);
    (void)__hip_atomic_load(f, __ATOMIC_ACQUIRE, __HIP_MEMORY_SCOPE_AGENT);
  }
  __syncthreads();
}
static __device__ __forceinline__ void publish0(int* f, int tid) {
  __threadfence();
  __syncthreads();
  if (tid == 0)
    __hip_atomic_store(f, 1, __ATOMIC_RELEASE, __HIP_MEMORY_SCOPE_AGENT);
}

// ---------------- small prep kernels ----------------

__global__ void k_sqrtp(const float* __restrict__ lp, float* __restrict__ sp,
                        float* __restrict__ pp) {
  int b = threadIdx.x;
  if (b < NB) sp[b] = expf(0.5f * lp[b]);
  if (b < 8) pp[b] = 0.f;
}

__global__ __launch_bounds__(128) void k_patches(const float* __restrict__ X,
                                                 const float* __restrict__ sp,
                                                 unsigned short* __restrict__ Phi,
                                                 unsigned short* __restrict__ Plo) {
  int d = blockIdx.x, s = blockIdx.y, t = threadIdx.x;
  int c = d / 9, r = d % 9, ky = r / 3, kx = r % 3;
  int p0 = t * 2;
  int yy = (p0 >> 4) + ky - 1;
  int xx0 = (p0 & 15) + kx - 1;
  bool oky = (yy >= 0 && yy < 16);
  bool ok0 = oky && (xx0 >= 0) && (xx0 < 16);
  bool ok1 = oky && (xx0 + 1 >= 0) && (xx0 + 1 < 16);
  int xo = yy * 16 + xx0;
  size_t base = ((size_t)s * ND + d) * NK + p0;
  for (int b = 0; b < NB; ++b) {
    float sb = sp[b];
    const float* xb = X + ((size_t)(s * NB + b) * CIN + c) * HWN;
    float v0 = ok0 ? xb[xo] * sb : 0.f;
    float v1 = ok1 ? xb[xo + 1] * sb : 0.f;
    unsigned short h0 = f2bf(v0), h1 = f2bf(v1);
    unsigned short l0 = f2bf(v0 - bf2f(h0)), l1 = f2bf(v1 - bf2f(h1));
    size_t idx = base + (size_t)b * HWN;
    *(unsigned int*)(Phi + idx) = (unsigned int)h0 | ((unsigned int)h1 << 16);
    *(unsigned int*)(Plo + idx) = (unsigned int)l0 | ((unsigned int)l1 << 16);
  }
}

__global__ __launch_bounds__(128) void k_ytt(const float* __restrict__ u,
                                             const float* __restrict__ sp,
                                             unsigned short* __restrict__ Yhi,
                                             unsigned short* __restrict__ Ylo) {
  int c = blockIdx.x, t = threadIdx.x;
  int p0 = t * 2;
  for (int b = 0; b < NB; ++b) {
    float sb = sp[b];
    const float* ub = u + ((size_t)b * NCOUT + c) * HWN + p0;
    float v0 = ub[0] * sb, v1 = ub[1] * sb;
    unsigned short h0 = f2bf(v0), h1 = f2bf(v1);
    unsigned short l0 = f2bf(v0 - bf2f(h0)), l1 = f2bf(v1 - bf2f(h1));
    size_t idx = (size_t)c * NK + (size_t)b * HWN + p0;
    *(unsigned int*)(Yhi + idx) = (unsigned int)h0 | ((unsigned int)h1 << 16);
    *(unsigned int*)(Ylo + idx) = (unsigned int)l0 | ((unsigned int)l1 << 16);
  }
}

// ---------------- bf16x3 MFMA XLX/XLY, K-split by 2 (partial sums) ----------------
__global__ __launch_bounds__(256) void k_gemm_mfma(
    const unsigned short* __restrict__ Phi, const unsigned short* __restrict__ Plo,
    const unsigned short* __restrict__ Yhi, const unsigned short* __restrict__ Ylo,
    float* __restrict__ prec, float* __restrict__ prec2,
    float* __restrict__ XLY, float* __restrict__ XLY2) {
  int jt = blockIdx.x, it = blockIdx.y;
  int s = blockIdx.z >> 1, kp = blockIdx.z & 1;
  bool isX = (jt <= it);
  if (!isX && jt < 9) return;
  int i0 = it * 128;
  int j0;
  const unsigned short *Bh, *Bl;
  if (isX) {
    j0 = jt * 128;
    Bh = Phi + ((size_t)s * ND + j0) * NK;
    Bl = Plo + ((size_t)s * ND + j0) * NK;
  } else {
    j0 = (jt - 9) * 128;
    Bh = Yhi + (size_t)j0 * NK;
    Bl = Ylo + (size_t)j0 * NK;
  }
  const unsigned short* Ah = Phi + ((size_t)s * ND + i0) * NK;
  const unsigned short* Al = Plo + ((size_t)s * ND + i0) * NK;

  __shared__ unsigned short sAh[4096], sAl[4096], sBh[4096], sBl[4096];
  int tid = threadIdx.x, wave = tid >> 6, lane = tid & 63;
  int wr = wave >> 1, wc = wave & 1;

  f32x4 zero = {0.f, 0.f, 0.f, 0.f};
  f32x4 acc[4][4];
#pragma unroll
  for (int m = 0; m < 4; ++m)
#pragma unroll
    for (int n = 0; n < 4; ++n) acc[m][n] = zero;

  const unsigned short* srcs[4] = {Ah, Al, Bh, Bl};
  unsigned short* dsts[4] = {sAh, sAl, sBh, sBl};
  int r0l = lane >> 2;
  int ke = (lane & 3) * 8;
  int arow0 = wr * 64 + (lane & 15);
  int brow0 = wc * 64 + (lane & 15);
  int koff = (lane >> 4) * 8;

  int kbeg = kp * (NK / 2), kend = kbeg + NK / 2;
  for (int k0 = kbeg; k0 < kend; k0 += 32) {
    __syncthreads();
#pragma unroll
    for (int f = 0; f < 4; ++f) {
#pragma unroll
      for (int cc = 0; cc < 2; ++cc) {
        int c = wave * 2 + cc;
        const unsigned short* g = srcs[f] + (size_t)(c * 16 + r0l) * NK + k0 + ke;
        unsigned short* l = dsts[f] + c * 512;
        __builtin_amdgcn_global_load_lds(
            (const __attribute__((address_space(1))) void*)g,
            (__attribute__((address_space(3))) void*)l, 16, 0, 0);
      }
    }
    __syncthreads();
    bf16x8 ah[4], al[4], bh[4], bl[4];
#pragma unroll
    for (int m = 0; m < 4; ++m) {
      int off = (arow0 + m * 16) * 32 + koff;
      ah[m] = *(const bf16x8*)&sAh[off];
      al[m] = *(const bf16x8*)&sAl[off];
    }
#pragma unroll
    for (int n = 0; n < 4; ++n) {
      int off = (brow0 + n * 16) * 32 + koff;
      bh[n] = *(const bf16x8*)&sBh[off];
      bl[n] = *(const bf16x8*)&sBl[off];
    }
#pragma unroll
    for (int m = 0; m < 4; ++m)
#pragma unroll
      for (int n = 0; n < 4; ++n) {
        acc[m][n] = __builtin_amdgcn_mfma_f32_16x16x32_bf16(ah[m], bh[n], acc[m][n], 0, 0, 0);
        acc[m][n] = __builtin_amdgcn_mfma_f32_16x16x32_bf16(ah[m], bl[n], acc[m][n], 0, 0, 0);
        acc[m][n] = __builtin_amdgcn_mfma_f32_16x16x32_bf16(al[m], bh[n], acc[m][n], 0, 0, 0);
      }
  }

  if (isX) {
    float* base = (kp ? prec2 : prec) + (size_t)s * D2;
#pragma unroll
    for (int m = 0; m < 4; ++m) {
      int row = i0 + wr * 64 + m * 16 + (lane >> 4) * 4;
#pragma unroll
      for (int n = 0; n < 4; ++n) {
        int col = j0 + wc * 64 + n * 16 + (lane & 15);
        float* cp = base + (size_t)row * ND + col;
#pragma unroll
        for (int r = 0; r < 4; ++r) cp[(size_t)r * ND] = acc[m][n][r];
      }
    }
  } else {
    float* base = (kp ? XLY2 : XLY) + (size_t)s * ND * NCOUT;
#pragma unroll
    for (int m = 0; m < 4; ++m) {
      int row = i0 + wr * 64 + m * 16 + (lane >> 4) * 4;
#pragma unroll
      for (int n = 0; n < 4; ++n) {
        int col = j0 + wc * 64 + n * 16 + (lane & 15);
        float* cp = base + (size_t)row * NCOUT + col;
#pragma unroll
        for (int r = 0; r < 4; ++r) cp[(size_t)r * NCOUT] = acc[m][n][r];
      }
    }
  }
}

// ---------------- persistent DAG Cholesky, 128x128 tiles ----------------
// 9 diag steps instead of 18 (hop cost is structural; halve the hop count).
// Diag factors 128x128 in-block via Schur: factor64(Q11) -> i11; C21 =
// A21 i11^T; Q22' = Q22 - C21 C21^T; factor64(Q22') -> i22; inv21 =
// -i22 (C21 i11). Writes the full 128x128 inverse DIRECTLY to iD (what
// k_solve2 consumes) -> k_invd128 deleted. Off-diag: trsm vs iD(bj).
// Flags fc[s*81 + bi*9 + bj]. All waits/publishes R2-style (tid0).

// factor64 on LDS buffers: Af holds SPD 64x64 (row-major [64][68]); fills Bf
// with identity, factors, leaves inverse in Bf, L in Af lower, writes logd.
static __device__ __forceinline__ void factor64_core(
    float* Af, float* Bf, int tid, int lane, int w, float* logdq) {
  float (*At)[68] = (float(*)[68])Af;
  float (*Bt)[68] = (float(*)[68])Bf;
  {
    int rr = tid >> 2, cb2 = (tid & 3) * 16;
#pragma unroll
    for (int m = 0; m < 16; ++m) Bt[rr][cb2 + m] = (rr == cb2 + m) ? 1.f : 0.f;
  }
  __syncthreads();
  float diagv = 1.f;
  for (int p = 0; p < 8; ++p) {
    int c0 = p * 8;
    if (w == 0) {
      float pa[8], xb[8];
#pragma unroll
      for (int e = 0; e < 8; ++e) {
        pa[e] = At[lane][c0 + e];
        xb[e] = Bt[c0 + e][lane];
      }
#pragma unroll
      for (int j = 0; j < 8; ++j) {
        float dj = rdlane(pa[j], c0 + j);
        float r0 = __builtin_amdgcn_rsqf(dj);
        r0 = r0 * (1.5f - 0.5f * dj * r0 * r0);  // one Newton step
        pa[j] *= r0;
        float xj = xb[j] * r0;
        xb[j] = xj;
        if (lane == c0 + j) diagv = dj * r0;
#pragma unroll
        for (int e = j + 1; e < 8; ++e) {
          float sv = rdlane(pa[j], c0 + e);
          pa[e] = fmaf(-pa[j], sv, pa[e]);
          xb[e] = fmaf(-sv, xj, xb[e]);
        }
      }
#pragma unroll
      for (int e = 0; e < 8; ++e) {
        At[lane][c0 + e] = pa[e];
        Bt[c0 + e][lane] = xb[e];
      }
    }
    __syncthreads();
    if (p < 7) {
      float La[8], Xp[8];
#pragma unroll
      for (int e = 0; e < 8; ++e) {
        La[e] = At[lane][c0 + e];
        Xp[e] = Bt[c0 + e][lane];
      }
      for (int c = c0 + 8 + w; c < 64; c += 4) {
        float Lc[8];
#pragma unroll
        for (int e = 0; e < 8; ++e) Lc[e] = At[c][c0 + e];
        float v = At[lane][c], vb = Bt[c][lane];
#pragma unroll
        for (int e = 0; e < 8; ++e) {
          v = fmaf(-La[e], Lc[e], v);
          vb = fmaf(-Lc[e], Xp[e], vb);
        }
        At[lane][c] = v;
        Bt[c][lane] = vb;
      }
      __syncthreads();
    }
  }
  if (w == 0) logdq[lane] = logf(diagv);
  __syncthreads();
}

__global__ __launch_bounds__(256, 2) void k_chol_dag(
    float* __restrict__ L, const float* __restrict__ Lp2,
    float* __restrict__ iD, float* __restrict__ logd,
    int* __restrict__ flags) {
  int t0 = blockIdx.x, s = blockIdx.y;
  int bi = 0;
  while ((bi + 1) * (bi + 2) / 2 <= t0) ++bi;
  int bj = t0 - bi * (bi + 1) / 2;
  int ib = bi * 128, jb = bj * 128;
  float* Ls = L + (size_t)s * D2;
  const float* Ps = Lp2 + (size_t)s * D2;
  int* fc = flags + s * 81;
  float* iDo = iD + ((size_t)(s * 9 + bi)) * 16384;  // diag out
  const float* iDq = iD + ((size_t)(s * 9 + bj)) * 16384;  // trsm in

  // S: 3 x 64x68 f32 buffers (52.2 KB); strip views SA/SB [32][132] alias.
  __shared__ float S[13056];
  float* A64 = S;
  float* B64 = S + 4352;
  float* C64 = S + 8704;
  float* SA = S;
  float* SB = S + 4352;

  int tid = threadIdx.x, tx = tid & 15, ty = tid >> 4;
  int lane = tid & 63, w = tid >> 6;

  // acc = prec + prec2 tile (+I on diag); 8x8 per thread (16x16 threads)
  float acc[8][8];
#pragma unroll
  for (int rr = 0; rr < 8; ++rr) {
    const float* p1 = Ls + (size_t)(ib + ty * 8 + rr) * ND + jb + tx * 8;
    const float* p2 = Ps + (size_t)(ib + ty * 8 + rr) * ND + jb + tx * 8;
    float4 v0 = *(const float4*)p1, v1 = *(const float4*)(p1 + 4);
    float4 q0 = *(const float4*)p2, q1 = *(const float4*)(p2 + 4);
    acc[rr][0] = v0.x + q0.x; acc[rr][1] = v0.y + q0.y;
    acc[rr][2] = v0.z + q0.z; acc[rr][3] = v0.w + q0.w;
    acc[rr][4] = v1.x + q1.x; acc[rr][5] = v1.y + q1.y;
    acc[rr][6] = v1.z + q1.z; acc[rr][7] = v1.w + q1.w;
  }
  if (bi == bj) {
#pragma unroll
    for (int rr = 0; rr < 8; ++rr)
#pragma unroll
      for (int e = 0; e < 8; ++e)
        if (ty * 8 + rr == tx * 8 + e) acc[rr][e] += 1.f;
  }

  // trailing updates: acc -= L(bi,k) @ L(bj,k)^T for k < bj (diag: k < bi)
  for (int k = 0; k < bj; ++k) {
    if (tid == 0) {
      while (__hip_atomic_load(&fc[bi * 9 + k], __ATOMIC_RELAXED,
                               __HIP_MEMORY_SCOPE_AGENT) == 0)
        __builtin_amdgcn_s_sleep(2);
      if (bi != bj)
        while (__hip_atomic_load(&fc[bj * 9 + k], __ATOMIC_RELAXED,
                                 __HIP_MEMORY_SCOPE_AGENT) == 0)
          __builtin_amdgcn_s_sleep(2);
      (void)__hip_atomic_load(&fc[bi * 9 + k], __ATOMIC_ACQUIRE,
                              __HIP_MEMORY_SCOPE_AGENT);
    }
    __syncthreads();
    for (int ks = 0; ks < 4; ++ks) {
      __syncthreads();
      {
        int i = tid >> 1, kb = (tid & 1) * 16;
        const float* sa = Ls + (size_t)(ib + i) * ND + k * 128 + ks * 32 + kb;
#pragma unroll
        for (int m = 0; m < 4; ++m) {
          float4 v = *(const float4*)(sa + m * 4);
          SA[(kb + m * 4 + 0) * 132 + i] = v.x;
          SA[(kb + m * 4 + 1) * 132 + i] = v.y;
          SA[(kb + m * 4 + 2) * 132 + i] = v.z;
          SA[(kb + m * 4 + 3) * 132 + i] = v.w;
        }
        if (bi != bj) {
          const float* sb = Ls + (size_t)(jb + i) * ND + k * 128 + ks * 32 + kb;
#pragma unroll
          for (int m = 0; m < 4; ++m) {
            float4 v = *(const float4*)(sb + m * 4);
            SB[(kb + m * 4 + 0) * 132 + i] = v.x;
            SB[(kb + m * 4 + 1) * 132 + i] = v.y;
            SB[(kb + m * 4 + 2) * 132 + i] = v.z;
            SB[(kb + m * 4 + 3) * 132 + i] = v.w;
          }
        }
      }
      __syncthreads();
      const float* SBu = (bi == bj) ? SA : SB;
#pragma unroll
      for (int kc = 0; kc < 32; ++kc) {
        float4 a0 = *(const float4*)&SA[kc * 132 + ty * 8];
        float4 a1 = *(const float4*)&SA[kc * 132 + ty * 8 + 4];
        float4 b0 = *(const float4*)&SBu[kc * 132 + tx * 8];
        float4 b1 = *(const float4*)&SBu[kc * 132 + tx * 8 + 4];
        float a[8] = {a0.x, a0.y, a0.z, a0.w, a1.x, a1.y, a1.z, a1.w};
        float b[8] = {b0.x, b0.y, b0.z, b0.w, b1.x, b1.y, b1.z, b1.w};
#pragma unroll
        for (int rr = 0; rr < 8; ++rr)
#pragma unroll
          for (int e = 0; e < 8; ++e) acc[rr][e] = fmaf(-a[rr], b[e], acc[rr][e]);
      }
    }
  }

  if (bi != bj) {
    // ---- off-diag: C = P @ iD(bj)^T (iD = full 128 inverse, lower-tri) ----
    waitflag0(&fc[bj * 9 + bj], tid);
    float c2[8][8];
#pragma unroll
    for (int rr = 0; rr < 8; ++rr)
#pragma unroll
      for (int e = 0; e < 8; ++e) c2[rr][e] = 0.f;
    for (int ks = 0; ks < 4; ++ks) {
      __syncthreads();
      if ((tx >> 2) == ks) {
#pragma unroll
        for (int rr = 0; rr < 8; ++rr)
#pragma unroll
          for (int e = 0; e < 8; ++e)
            SA[(tx * 8 + e - ks * 32) * 132 + ty * 8 + rr] = acc[rr][e];
      }
      {
        int c = tid >> 1, kb = (tid & 1) * 16;
        const float* sb = iDq + (size_t)c * 128 + ks * 32 + kb;
#pragma unroll
        for (int m = 0; m < 4; ++m) {
          float4 v = *(const float4*)(sb + m * 4);
          SB[(kb + m * 4 + 0) * 132 + c] = v.x;
          SB[(kb + m * 4 + 1) * 132 + c] = v.y;
          SB[(kb + m * 4 + 2) * 132 + c] = v.z;
          SB[(kb + m * 4 + 3) * 132 + c] = v.w;
        }
      }
      __syncthreads();
#pragma unroll
      for (int kc = 0; kc < 32; ++kc) {
        float4 a0 = *(const float4*)&SA[kc * 132 + ty * 8];
        float4 a1 = *(const float4*)&SA[kc * 132 + ty * 8 + 4];
        float4 b0 = *(const float4*)&SB[kc * 132 + tx * 8];
        float4 b1 = *(const float4*)&SB[kc * 132 + tx * 8 + 4];
        float a[8] = {a0.x, a0.y, a0.z, a0.w, a1.x, a1.y, a1.z, a1.w};
        float b[8] = {b0.x, b0.y, b0.z, b0.w, b1.x, b1.y, b1.z, b1.w};
#pragma unroll
        for (int rr = 0; rr < 8; ++rr)
#pragma unroll
          for (int e = 0; e < 8; ++e) c2[rr][e] = fmaf(a[rr], b[e], c2[rr][e]);
      }
    }
#pragma unroll
    for (int rr = 0; rr < 8; ++rr) {
      float* dst = Ls + (size_t)(ib + ty * 8 + rr) * ND + jb + tx * 8;
      float4 v0 = {c2[rr][0], c2[rr][1], c2[rr][2], c2[rr][3]};
      float4 v1 = {c2[rr][4], c2[rr][5], c2[rr][6], c2[rr][7]};
      *(float4*)dst = v0;
      *(float4*)(dst + 4) = v1;
    }
    publish0(&fc[bi * 9 + bj], tid);
  } else {
    // ---- diag: factor 128x128 via Schur, produce full inverse in iD ----
    __syncthreads();  // strip reads done before overwriting S
    // step 1: Q11 -> A64; factor -> L11 (A64), i11 (B64)
    if (ty < 8 && tx < 8) {
#pragma unroll
      for (int rr = 0; rr < 8; ++rr)
#pragma unroll
        for (int e = 0; e < 8; ++e)
          A64[(ty * 8 + rr) * 68 + tx * 8 + e] = acc[rr][e];
    }
    factor64_core(A64, B64, tid, lane, w, logd + (size_t)s * ND + ib);
    // step 2: iD Q11 = i11, Q12 = 0
    {
      int r = tid >> 2, c4 = (tid & 3) * 16;
      float4 z = {0.f, 0.f, 0.f, 0.f};
#pragma unroll
      for (int m = 0; m < 4; ++m) {
        *(float4*)(iDo + (size_t)r * 128 + c4 + m * 4) =
            *(const float4*)&B64[r * 68 + c4 + m * 4];
        *(float4*)(iDo + (size_t)r * 128 + 64 + c4 + m * 4) = z;
      }
    }
    // step 3: A64 <- A21t; C64 <- i11t
    if (ty >= 8 && tx < 8) {
#pragma unroll
      for (int rr = 0; rr < 8; ++rr)
#pragma unroll
        for (int e = 0; e < 8; ++e)
          A64[(tx * 8 + e) * 68 + (ty - 8) * 8 + rr] = acc[rr][e];
    }
    {
      int r = tid >> 2, c4 = (tid & 3) * 16;
#pragma unroll
      for (int m = 0; m < 16; ++m)
        C64[(c4 + m) * 68 + r] = B64[r * 68 + c4 + m];
    }
    __syncthreads();
    // step 4: GEMM1 c21 = A21 · i11^T  (A-op A21t, B-op i11t), 16x16 thr x4x4
    float c21[4][4] = {};
#pragma unroll
    for (int kc = 0; kc < 64; ++kc) {
      float4 a4 = *(const float4*)&A64[kc * 68 + ty * 4];
      float4 b4 = *(const float4*)&C64[kc * 68 + tx * 4];
      float a[4] = {a4.x, a4.y, a4.z, a4.w};
      float b[4] = {b4.x, b4.y, b4.z, b4.w};
#pragma unroll
      for (int rr = 0; rr < 4; ++rr)
#pragma unroll
        for (int e = 0; e < 4; ++e) c21[rr][e] = fmaf(a[rr], b[e], c21[rr][e]);
    }
    __syncthreads();
    // C64 <- C21t; A64 <- Q22
#pragma unroll
    for (int rr = 0; rr < 4; ++rr)
#pragma unroll
      for (int e = 0; e < 4; ++e)
        C64[(tx * 4 + e) * 68 + ty * 4 + rr] = c21[rr][e];
    if (ty >= 8 && tx >= 8) {
#pragma unroll
      for (int rr = 0; rr < 8; ++rr)
#pragma unroll
        for (int e = 0; e < 8; ++e)
          A64[((ty - 8) * 8 + rr) * 68 + (tx - 8) * 8 + e] = acc[rr][e];
    }
    __syncthreads();
    // step 5: a22 = Q22 - C21 C21^T ; m4 = C21 · i11
    float a22[4][4], m4[4][4] = {};
#pragma unroll
    for (int rr = 0; rr < 4; ++rr) {
      float4 v = *(const float4*)&A64[(ty * 4 + rr) * 68 + tx * 4];
      a22[rr][0] = v.x; a22[rr][1] = v.y; a22[rr][2] = v.z; a22[rr][3] = v.w;
    }
#pragma unroll
    for (int kc = 0; kc < 64; ++kc) {
      float4 a4 = *(const float4*)&C64[kc * 68 + ty * 4];   // C21t[k][r]
      float4 b4 = *(const float4*)&C64[kc * 68 + tx * 4];   // C21t[k][c]
      float4 g4 = *(const float4*)&B64[kc * 68 + tx * 4];   // i11[k][c]
      float a[4] = {a4.x, a4.y, a4.z, a4.w};
      float b[4] = {b4.x, b4.y, b4.z, b4.w};
      float g[4] = {g4.x, g4.y, g4.z, g4.w};
#pragma unroll
      for (int rr = 0; rr < 4; ++rr)
#pragma unroll
        for (int e = 0; e < 4; ++e) {
          a22[rr][e] = fmaf(-a[rr], b[e], a22[rr][e]);
          m4[rr][e] = fmaf(a[rr], g[e], m4[rr][e]);
        }
    }
    __syncthreads();
    // write back: A64 <- a22 (Schur complement), C64 <- M (row-major)
#pragma unroll
    for (int rr = 0; rr < 4; ++rr) {
      float4 va = {a22[rr][0], a22[rr][1], a22[rr][2], a22[rr][3]};
      float4 vm = {m4[rr][0], m4[rr][1], m4[rr][2], m4[rr][3]};
      *(float4*)&A64[(ty * 4 + rr) * 68 + tx * 4] = va;
      *(float4*)&C64[(ty * 4 + rr) * 68 + tx * 4] = vm;
    }
    // step 6: factor Schur -> i22 (B64)
    factor64_core(A64, B64, tid, lane, w, logd + (size_t)s * ND + ib + 64);
    // step 7: i21 = i22 · M; iD Q21 = -i21, Q22 = i22
    float i21[4][4] = {};
#pragma unroll
    for (int p = 0; p < 64; ++p) {
      float a[4];
#pragma unroll
      for (int rr = 0; rr < 4; ++rr) a[rr] = B64[(ty * 4 + rr) * 68 + p];
      float4 b4 = *(const float4*)&C64[p * 68 + tx * 4];
      float b[4] = {b4.x, b4.y, b4.z, b4.w};
#pragma unroll
      for (int rr = 0; rr < 4; ++rr)
#pragma unroll
        for (int e = 0; e < 4; ++e) i21[rr][e] = fmaf(a[rr], b[e], i21[rr][e]);
    }
#pragma unroll
    for (int rr = 0; rr < 4; ++rr) {
      float4 v = {-i21[rr][0], -i21[rr][1], -i21[rr][2], -i21[rr][3]};
      *(float4*)(iDo + (size_t)(64 + ty * 4 + rr) * 128 + tx * 4) = v;
    }
    {
      int r = tid >> 2, c4 = (tid & 3) * 16;
#pragma unroll
      for (int m = 0; m < 4; ++m)
        *(float4*)(iDo + (size_t)(64 + r) * 128 + 64 + c4 + m * 4) =
            *(const float4*)&B64[r * 68 + c4 + m * 4];
    }
    publish0(&fc[bi * 9 + bi], tid);
  }
}

// ---------------- merged persistent fwd+bwd solve (fused addz/writewm) ----------------
__global__ __launch_bounds__(256) void k_solve2(
    const float* __restrict__ L, const float* __restrict__ iD,
    const float* __restrict__ B1, const float* __restrict__ B2,
    const float* __restrict__ Z, float* __restrict__ Xf, float* __restrict__ Xb,
    float* __restrict__ Wm, float* __restrict__ pp, int* __restrict__ flags) {
  int r = blockIdx.x, ct = blockIdx.y, s = blockIdx.z;
  int rb = r * 128, cb = ct * 64;
  const float* Ls = L + (size_t)s * D2;
  const float* Dq = iD + ((size_t)(s * 9 + r)) * 16384;
  float* Xfs = Xf + (size_t)s * ND * NCOUT;
  float* Xbs = Xb + (size_t)s * ND * NCOUT;
  int fbf = 1296 + (s * 4 + ct) * 9;
  int fbb = 1440 + (s * 4 + ct) * 9;

  __shared__ float sA[32][132];
  __shared__ float sB[32][68];
  __shared__ float red[8];
  int tid = threadIdx.x, tx = tid & 15, ty = tid >> 4;
  int wave = tid >> 6, lane = tid & 63;

  // ======== forward ========
  float acc[8][4];
#pragma unroll
  for (int ii = 0; ii < 8; ++ii) {
    size_t idx = (size_t)s * ND * NCOUT + (size_t)(rb + ty * 8 + ii) * NCOUT + cb + tx * 4;
    float4 v = *(const float4*)(B1 + idx);
    float4 v2 = *(const float4*)(B2 + idx);
    acc[ii][0] = v.x + v2.x; acc[ii][1] = v.y + v2.y;
    acc[ii][2] = v.z + v2.z; acc[ii][3] = v.w + v2.w;
  }
  for (int q = 0; q < r; ++q) {
    waitflag0(&flags[fbf + q], tid);
    int qb = q * 128;
    for (int kk = 0; kk < 4; ++kk) {
      __syncthreads();
      {
        int i = tid >> 1, kb = (tid & 1) * 16;
        const float* src = Ls + (size_t)(rb + i) * ND + qb + kk * 32 + kb;
#pragma unroll
        for (int m = 0; m < 4; ++m) {
          float4 v = *(const float4*)(src + m * 4);
          sA[kb + m * 4 + 0][i] = v.x;
          sA[kb + m * 4 + 1][i] = v.y;
          sA[kb + m * 4 + 2][i] = v.z;
          sA[kb + m * 4 + 3][i] = v.w;
        }
      }
      {
        int k = tid >> 3, jb2 = (tid & 7) * 8;
        const float* src = Xfs + (size_t)(qb + kk * 32 + k) * NCOUT + cb + jb2;
        float4 v0 = *(const float4*)src;
        float4 v1 = *(const float4*)(src + 4);
        *(float4*)&sB[k][jb2] = v0;
        *(float4*)&sB[k][jb2 + 4] = v1;
      }
      __syncthreads();
#pragma unroll
      for (int k = 0; k < 32; ++k) {
        float4 a0 = *(const float4*)&sA[k][ty * 8];
        float4 a1 = *(const float4*)&sA[k][ty * 8 + 4];
        float4 b0 = *(const float4*)&sB[k][tx * 4];
        float a[8] = {a0.x, a0.y, a0.z, a0.w, a1.x, a1.y, a1.z, a1.w};
        float b[4] = {b0.x, b0.y, b0.z, b0.w};
#pragma unroll
        for (int ii = 0; ii < 8; ++ii)
#pragma unroll
          for (int j = 0; j < 4; ++j) acc[ii][j] = fmaf(-a[ii], b[j], acc[ii][j]);
      }
    }
  }
  float acc2[8][4] = {};
  for (int kk = 0; kk < 4; ++kk) {
    __syncthreads();
    if ((ty >> 2) == kk) {
      int kloc = ty * 8 - kk * 32;
#pragma unroll
      for (int ii = 0; ii < 8; ++ii) {
        float4 v = {acc[ii][0], acc[ii][1], acc[ii][2], acc[ii][3]};
        *(float4*)&sB[kloc + ii][tx * 4] = v;
      }
    }
    {
      int i = tid >> 1, kb = (tid & 1) * 16;
      const float* src = Dq + (size_t)i * 128 + kk * 32 + kb;
#pragma unroll
      for (int m = 0; m < 4; ++m) {
        float4 v = *(const float4*)(src + m * 4);
        sA[kb + m * 4 + 0][i] = v.x;
        sA[kb + m * 4 + 1][i] = v.y;
        sA[kb + m * 4 + 2][i] = v.z;
        sA[kb + m * 4 + 3][i] = v.w;
      }
    }
    __syncthreads();
#pragma unroll
    for (int k = 0; k < 32; ++k) {
      float4 a0 = *(const float4*)&sA[k][ty * 8];
      float4 a1 = *(const float4*)&sA[k][ty * 8 + 4];
      float4 b0 = *(const float4*)&sB[k][tx * 4];
      float a[8] = {a0.x, a0.y, a0.z, a0.w, a1.x, a1.y, a1.z, a1.w};
      float b[4] = {b0.x, b0.y, b0.z, b0.w};
#pragma unroll
      for (int ii = 0; ii < 8; ++ii)
#pragma unroll
        for (int j = 0; j < 4; ++j) acc2[ii][j] = fmaf(a[ii], b[j], acc2[ii][j]);
    }
  }
#pragma unroll
  for (int ii = 0; ii < 8; ++ii) {
    float4 v = {acc2[ii][0], acc2[ii][1], acc2[ii][2], acc2[ii][3]};
    *(float4*)(Xfs + (size_t)(rb + ty * 8 + ii) * NCOUT + cb + tx * 4) = v;
  }
  __threadfence();
  __syncthreads();
  if (tid == 0)
    __hip_atomic_store(&flags[fbf + r], 1, __ATOMIC_RELEASE,
                       __HIP_MEMORY_SCOPE_AGENT);

  // ======== backward (init from fwd result in registers) ========
#pragma unroll
  for (int ii = 0; ii < 8; ++ii)
#pragma unroll
    for (int j = 0; j < 4; ++j) acc[ii][j] = acc2[ii][j];

  float zp = 0.f;
  for (int kk = 0; kk < 4; ++kk) {
    __syncthreads();
    {
      int c = tid >> 2, d8 = (tid & 3) * 8;
      const float* src = Z + ((size_t)(s * NCOUT) + cb + c) * ND + rb + kk * 32 + d8;
      float4 v0 = *(const float4*)src;
      float4 v1 = *(const float4*)(src + 4);
      sA[d8 + 0][c] = v0.x; sA[d8 + 1][c] = v0.y; sA[d8 + 2][c] = v0.z; sA[d8 + 3][c] = v0.w;
      sA[d8 + 4][c] = v1.x; sA[d8 + 5][c] = v1.y; sA[d8 + 6][c] = v1.z; sA[d8 + 7][c] = v1.w;
      zp += v0.x * v0.x + v0.y * v0.y + v0.z * v0.z + v0.w * v0.w;
      zp += v1.x * v1.x + v1.y * v1.y + v1.z * v1.z + v1.w * v1.w;
    }
    __syncthreads();
    if ((ty >> 2) == kk) {
      int kloc = ty * 8 - kk * 32;
#pragma unroll
      for (int ii = 0; ii < 8; ++ii) {
        float4 v = *(const float4*)&sA[kloc + ii][tx * 4];
        acc[ii][0] += v.x; acc[ii][1] += v.y; acc[ii][2] += v.z; acc[ii][3] += v.w;
      }
    }
  }
#pragma unroll
  for (int m2 = 32; m2 >= 1; m2 >>= 1) zp += __shfl_xor(zp, m2, 64);
  if (lane == 0) red[wave] = zp;
  __syncthreads();
  if (tid == 0) atomicAdd(pp + s, red[0] + red[1] + red[2] + red[3]);

  for (int q = 8; q > r; --q) {
    waitflag0(&flags[fbb + q], tid);
    int qb = q * 128;
    for (int kk = 0; kk < 4; ++kk) {
      __syncthreads();
      {
        int k = tid >> 3, ib2 = (tid & 7) * 16;
        const float* src = Ls + (size_t)(qb + kk * 32 + k) * ND + rb + ib2;
#pragma unroll
        for (int m = 0; m < 4; ++m)
          *(float4*)&sA[k][ib2 + m * 4] = *(const float4*)(src + m * 4);
      }
      {
        int k = tid >> 3, jb2 = (tid & 7) * 8;
        const float* src = Xbs + (size_t)(qb + kk * 32 + k) * NCOUT + cb + jb2;
        float4 v0 = *(const float4*)src;
        float4 v1 = *(const float4*)(src + 4);
        *(float4*)&sB[k][jb2] = v0;
        *(float4*)&sB[k][jb2 + 4] = v1;
      }
      __syncthreads();
#pragma unroll
      for (int k = 0; k < 32; ++k) {
        float4 a0 = *(const float4*)&sA[k][ty * 8];
        float4 a1 = *(const float4*)&sA[k][ty * 8 + 4];
        float4 b0 = *(const float4*)&sB[k][tx * 4];
        float a[8] = {a0.x, a0.y, a0.z, a0.w, a1.x, a1.y, a1.z, a1.w};
        float b[4] = {b0.x, b0.y, b0.z, b0.w};
#pragma unroll
        for (int ii = 0; ii < 8; ++ii)
#pragma unroll
          for (int j = 0; j < 4; ++j) acc[ii][j] = fmaf(-a[ii], b[j], acc[ii][j]);
      }
    }
  }
#pragma unroll
  for (int ii = 0; ii < 8; ++ii)
#pragma unroll
    for (int j = 0; j < 4; ++j) acc2[ii][j] = 0.f;
  for (int kk = 0; kk < 4; ++kk) {
    __syncthreads();
    if ((ty >> 2) == kk) {
      int kloc = ty * 8 - kk * 32;
#pragma unroll
      for (int ii = 0; ii < 8; ++ii) {
        float4 v = {acc[ii][0], acc[ii][1], acc[ii][2], acc[ii][3]};
        *(float4*)&sB[kloc + ii][tx * 4] = v;
      }
    }
    {
      int k = tid >> 3, ib2 = (tid & 7) * 16;
      const float* src = Dq + (size_t)(kk * 32 + k) * 128 + ib2;
#pragma unroll
      for (int m = 0; m < 4; ++m)
        *(float4*)&sA[k][ib2 + m * 4] = *(const float4*)(src + m * 4);
    }
    __syncthreads();
#pragma unroll
    for (int k = 0; k < 32; ++k) {
      float4 a0 = *(const float4*)&sA[k][ty * 8];
      float4 a1 = *(const float4*)&sA[k][ty * 8 + 4];
      float4 b0 = *(const float4*)&sB[k][tx * 4];
      float a[8] = {a0.x, a0.y, a0.z, a0.w, a1.x, a1.y, a1.z, a1.w};
      float b[4] = {b0.x, b0.y, b0.z, b0.w};
#pragma unroll
      for (int ii = 0; ii < 8; ++ii)
#pragma unroll
        for (int j = 0; j < 4; ++j) acc2[ii][j] = fmaf(a[ii], b[j], acc2[ii][j]);
    }
  }
#pragma unroll
  for (int ii = 0; ii < 8; ++ii) {
    float4 v = {acc2[ii][0], acc2[ii][1], acc2[ii][2], acc2[ii][3]};
    *(float4*)(Xbs + (size_t)(rb + ty * 8 + ii) * NCOUT + cb + tx * 4) = v;
  }
  __threadfence();
  __syncthreads();
  if (tid == 0)
    __hip_atomic_store(&flags[fbb + r], 1, __ATOMIC_RELEASE,
                       __HIP_MEMORY_SCOPE_AGENT);
  float wp = 0.f;
#pragma unroll
  for (int ii = 0; ii < 8; ++ii)
#pragma unroll
    for (int j = 0; j < 4; ++j) wp += acc2[ii][j] * acc2[ii][j];
#pragma unroll
  for (int m2 = 32; m2 >= 1; m2 >>= 1) wp += __shfl_xor(wp, m2, 64);
  __syncthreads();
  if (lane == 0) red[wave] = wp;
  __syncthreads();
  if (tid == 0) atomicAdd(pp + 4 + s, red[0] + red[1] + red[2] + red[3]);
  for (int kk = 0; kk < 4; ++kk) {
    __syncthreads();
    if ((ty >> 2) == kk) {
      int kloc = ty * 8 - kk * 32;
#pragma unroll
      for (int ii = 0; ii < 8; ++ii) {
        float4 v = {acc2[ii][0], acc2[ii][1], acc2[ii][2], acc2[ii][3]};
        *(float4*)&sB[kloc + ii][tx * 4] = v;
      }
    }
    __syncthreads();
    {
      int c = tid >> 2, d8 = (tid & 3) * 8;
      float t0 = sB[d8 + 0][c], t1 = sB[d8 + 1][c], t2 = sB[d8 + 2][c], t3 = sB[d8 + 3][c];
      float t4 = sB[d8 + 4][c], t5 = sB[d8 + 5][c], t6 = sB[d8 + 6][c], t7 = sB[d8 + 7][c];
      float* dst = Wm + ((size_t)(s * NCOUT) + cb + c) * ND + rb + kk * 32 + d8;
      float4 w0 = {t0, t1, t2, t3}, w1 = {t4, t5, t6, t7};
      *(float4*)dst = w0;
      *(float4*)(dst + 4) = w1;
    }
  }
}

__global__ __launch_bounds__(256) void k_finalize(const float* __restrict__ logd,
                                                  const float* __restrict__ pp,
                                                  float* __restrict__ out) {
  int s = blockIdx.x, tid = threadIdx.x;
  __shared__ float r0[256];
  float l = 0.f;
  for (int i = tid; i < ND; i += 256) l += logd[s * ND + i];
  r0[tid] = l;
  __syncthreads();
  for (int off = 128; off; off >>= 1) {
    if (tid < off) r0[tid] += r0[tid + off];
    __syncthreads();
  }
  if (tid == 0) {
    float logdet = 2.0f * r0[0];
    out[s] = 0.5f * (pp[s] - pp[4 + s]) - 128.0f * logdet;
  }
}

// ---------------- launcher ----------------
extern "C" void kernel_launch(void* const* d_in, const int* in_sizes, int n_in,
                              void* d_out, int out_size, void* d_ws, size_t ws_size,
                              hipStream_t stream) {
  const float* X = (const float*)d_in[0];
  const float* u = (const float*)d_in[1];
  const float* lp = (const float*)d_in[2];
  const float* Z = (const float*)d_in[3];
  float* out = (float*)d_out;

  float* ws = (float*)d_ws;
  float* sp    = ws;                                    // 64
  float* invd  = sp + 64;                               // 4608 (unused, layout kept)
  float* logd  = invd + (size_t)NS * ND;                // 4608
  float* pp    = logd + (size_t)NS * ND;                // 64
  int*   flags = (int*)(pp + 64);                       // 2048 ints
  float* iD    = (float*)(flags + 2048);                // 4*9*16384
  float* iA64  = iD + (size_t)NS * 9 * 16384;           // 4*18*4096 (unused now)
  float* Xf    = iA64 + (size_t)NS * 18 * 4096;         // 4*1152*256
  float* Xb    = Xf + (size_t)NS * ND * NCOUT;          // 4*1152*256
  float* prec  = Xb + (size_t)NS * ND * NCOUT;          // 4*1152*1152
  float* prec2 = prec + (size_t)NS * D2;                // 4*1152*1152
  float* XLY   = prec2 + (size_t)NS * D2;               // 4*1152*256
  float* XLY2  = XLY + (size_t)NS * ND * NCOUT;         // 4*1152*256
  unsigned short* Phi = (unsigned short*)(XLY2 + (size_t)NS * ND * NCOUT);
  unsigned short* Plo = Phi + (size_t)NS * ND * NK;
  unsigned short* Yhi = Plo + (size_t)NS * ND * NK;
  unsigned short* Ylo = Yhi + (size_t)NCOUT * NK;

  hipMemsetAsync(flags, 0, 2048 * sizeof(int), stream);
  k_sqrtp<<<1, 64, 0, stream>>>(lp, sp, pp);
  k_patches<<<dim3(ND, NS), 128, 0, stream>>>(X, sp, Phi, Plo);
  k_ytt<<<NCOUT, 128, 0, stream>>>(u, sp, Yhi, Ylo);
  k_gemm_mfma<<<dim3(11, 9, NS * 2), 256, 0, stream>>>(Phi, Plo, Yhi, Ylo, prec,
                                                       prec2, XLY, XLY2);
  k_chol_dag<<<dim3(45, NS), 256, 0, stream>>>(prec, prec2, iD, logd, flags);
  k_solve2<<<dim3(9, 4, NS), 256, 0, stream>>>(prec, iD, XLY, XLY2, Z, Xf, Xb,
                                               out, pp, flags);
  k_finalize<<<NS, 256, 0, stream>>>(logd, pp, out + (size_t)NS * NCOUT * ND);
}

// Round 9
// 1441.878 us; speedup vs baseline: 1.4714x; 1.4714x over previous
//
#include <hip/hip_runtime.h>
#include <math.h>

#define NS 4
#define NB 32
#define CIN 128
#define NCOUT 256
#define HWN 256
#define ND 1152
#define NK 8192   // NB*HWN
static const size_t D2 = (size_t)ND * ND;

typedef __attribute__((ext_vector_type(8))) short bf16x8;
typedef __attribute__((ext_vector_type(4))) float f32x4;

static __device__ inline unsigned short f2bf(float x) {
  unsigned int u = __float_as_uint(x);
  unsigned int r = (u + 0x7fffu + ((u >> 16) & 1u)) >> 16;
  return (unsigned short)r;
}
static __device__ inline float bf2f(unsigned short h) {
  return __uint_as_float(((unsigned int)h) << 16);
}
static __device__ inline float rdlane(float v, int l) {
  return __int_as_float(__builtin_amdgcn_readlane(__float_as_int(v), l));
}
// R2-proven: tid0 polls (one acquire), barrier broadcasts.
static __device__ __forceinline__ void waitflag0(const int* f, int tid) {
  if (tid == 0) {
    while (__hip_atomic_load(f, __ATOMIC_RELAXED, __HIP_MEMORY_SCOPE_AGENT) == 0)
      __builtin_amdgcn_s_sleep(2);
    (void)__hip_atomic_load(f, __ATOMIC_ACQUIRE, __HIP_MEMORY_SCOPE_AGENT);
  }
  __syncthreads();
}

// ---------------- small prep kernels ----------------

__global__ void k_sqrtp(const float* __restrict__ lp, float* __restrict__ sp,
                        float* __restrict__ pp) {
  int b = threadIdx.x;
  if (b < NB) sp[b] = expf(0.5f * lp[b]);
  if (b < 8) pp[b] = 0.f;
}

__global__ __launch_bounds__(128) void k_patches(const float* __restrict__ X,
                                                 const float* __restrict__ sp,
                                                 unsigned short* __restrict__ Phi,
                                                 unsigned short* __restrict__ Plo) {
  int d = blockIdx.x, s = blockIdx.y, t = threadIdx.x;
  int c = d / 9, r = d % 9, ky = r / 3, kx = r % 3;
  int p0 = t * 2;
  int yy = (p0 >> 4) + ky - 1;
  int xx0 = (p0 & 15) + kx - 1;
  bool oky = (yy >= 0 && yy < 16);
  bool ok0 = oky && (xx0 >= 0) && (xx0 < 16);
  bool ok1 = oky && (xx0 + 1 >= 0) && (xx0 + 1 < 16);
  int xo = yy * 16 + xx0;
  size_t base = ((size_t)s * ND + d) * NK + p0;
  for (int b = 0; b < NB; ++b) {
    float sb = sp[b];
    const float* xb = X + ((size_t)(s * NB + b) * CIN + c) * HWN;
    float v0 = ok0 ? xb[xo] * sb : 0.f;
    float v1 = ok1 ? xb[xo + 1] * sb : 0.f;
    unsigned short h0 = f2bf(v0), h1 = f2bf(v1);
    unsigned short l0 = f2bf(v0 - bf2f(h0)), l1 = f2bf(v1 - bf2f(h1));
    size_t idx = base + (size_t)b * HWN;
    *(unsigned int*)(Phi + idx) = (unsigned int)h0 | ((unsigned int)h1 << 16);
    *(unsigned int*)(Plo + idx) = (unsigned int)l0 | ((unsigned int)l1 << 16);
  }
}

__global__ __launch_bounds__(128) void k_ytt(const float* __restrict__ u,
                                             const float* __restrict__ sp,
                                             unsigned short* __restrict__ Yhi,
                                             unsigned short* __restrict__ Ylo) {
  int c = blockIdx.x, t = threadIdx.x;
  int p0 = t * 2;
  for (int b = 0; b < NB; ++b) {
    float sb = sp[b];
    const float* ub = u + ((size_t)b * NCOUT + c) * HWN + p0;
    float v0 = ub[0] * sb, v1 = ub[1] * sb;
    unsigned short h0 = f2bf(v0), h1 = f2bf(v1);
    unsigned short l0 = f2bf(v0 - bf2f(h0)), l1 = f2bf(v1 - bf2f(h1));
    size_t idx = (size_t)c * NK + (size_t)b * HWN + p0;
    *(unsigned int*)(Yhi + idx) = (unsigned int)h0 | ((unsigned int)h1 << 16);
    *(unsigned int*)(Ylo + idx) = (unsigned int)l0 | ((unsigned int)l1 << 16);
  }
}

// ---------------- bf16x3 MFMA XLX/XLY, K-split by 2 (partial sums) ----------------
__global__ __launch_bounds__(256) void k_gemm_mfma(
    const unsigned short* __restrict__ Phi, const unsigned short* __restrict__ Plo,
    const unsigned short* __restrict__ Yhi, const unsigned short* __restrict__ Ylo,
    float* __restrict__ prec, float* __restrict__ prec2,
    float* __restrict__ XLY, float* __restrict__ XLY2) {
  int jt = blockIdx.x, it = blockIdx.y;
  int s = blockIdx.z >> 1, kp = blockIdx.z & 1;
  bool isX = (jt <= it);
  if (!isX && jt < 9) return;
  int i0 = it * 128;
  int j0;
  const unsigned short *Bh, *Bl;
  if (isX) {
    j0 = jt * 128;
    Bh = Phi + ((size_t)s * ND + j0) * NK;
    Bl = Plo + ((size_t)s * ND + j0) * NK;
  } else {
    j0 = (jt - 9) * 128;
    Bh = Yhi + (size_t)j0 * NK;
    Bl = Ylo + (size_t)j0 * NK;
  }
  const unsigned short* Ah = Phi + ((size_t)s * ND + i0) * NK;
  const unsigned short* Al = Plo + ((size_t)s * ND + i0) * NK;

  __shared__ unsigned short sAh[4096], sAl[4096], sBh[4096], sBl[4096];
  int tid = threadIdx.x, wave = tid >> 6, lane = tid & 63;
  int wr = wave >> 1, wc = wave & 1;

  f32x4 zero = {0.f, 0.f, 0.f, 0.f};
  f32x4 acc[4][4];
#pragma unroll
  for (int m = 0; m < 4; ++m)
#pragma unroll
    for (int n = 0; n < 4; ++n) acc[m][n] = zero;

  const unsigned short* srcs[4] = {Ah, Al, Bh, Bl};
  unsigned short* dsts[4] = {sAh, sAl, sBh, sBl};
  int r0l = lane >> 2;
  int ke = (lane & 3) * 8;
  int arow0 = wr * 64 + (lane & 15);
  int brow0 = wc * 64 + (lane & 15);
  int koff = (lane >> 4) * 8;

  int kbeg = kp * (NK / 2), kend = kbeg + NK / 2;
  for (int k0 = kbeg; k0 < kend; k0 += 32) {
    __syncthreads();
#pragma unroll
    for (int f = 0; f < 4; ++f) {
#pragma unroll
      for (int cc = 0; cc < 2; ++cc) {
        int c = wave * 2 + cc;
        const unsigned short* g = srcs[f] + (size_t)(c * 16 + r0l) * NK + k0 + ke;
        unsigned short* l = dsts[f] + c * 512;
        __builtin_amdgcn_global_load_lds(
            (const __attribute__((address_space(1))) void*)g,
            (__attribute__((address_space(3))) void*)l, 16, 0, 0);
      }
    }
    __syncthreads();
    bf16x8 ah[4], al[4], bh[4], bl[4];
#pragma unroll
    for (int m = 0; m < 4; ++m) {
      int off = (arow0 + m * 16) * 32 + koff;
      ah[m] = *(const bf16x8*)&sAh[off];
      al[m] = *(const bf16x8*)&sAl[off];
    }
#pragma unroll
    for (int n = 0; n < 4; ++n) {
      int off = (brow0 + n * 16) * 32 + koff;
      bh[n] = *(const bf16x8*)&sBh[off];
      bl[n] = *(const bf16x8*)&sBl[off];
    }
#pragma unroll
    for (int m = 0; m < 4; ++m)
#pragma unroll
      for (int n = 0; n < 4; ++n) {
        acc[m][n] = __builtin_amdgcn_mfma_f32_16x16x32_bf16(ah[m], bh[n], acc[m][n], 0, 0, 0);
        acc[m][n] = __builtin_amdgcn_mfma_f32_16x16x32_bf16(ah[m], bl[n], acc[m][n], 0, 0, 0);
        acc[m][n] = __builtin_amdgcn_mfma_f32_16x16x32_bf16(al[m], bh[n], acc[m][n], 0, 0, 0);
      }
  }

  if (isX) {
    float* base = (kp ? prec2 : prec) + (size_t)s * D2;
#pragma unroll
    for (int m = 0; m < 4; ++m) {
      int row = i0 + wr * 64 + m * 16 + (lane >> 4) * 4;
#pragma unroll
      for (int n = 0; n < 4; ++n) {
        int col = j0 + wc * 64 + n * 16 + (lane & 15);
        float* cp = base + (size_t)row * ND + col;
#pragma unroll
        for (int r = 0; r < 4; ++r) cp[(size_t)r * ND] = acc[m][n][r];
      }
    }
  } else {
    float* base = (kp ? XLY2 : XLY) + (size_t)s * ND * NCOUT;
#pragma unroll
    for (int m = 0; m < 4; ++m) {
      int row = i0 + wr * 64 + m * 16 + (lane >> 4) * 4;
#pragma unroll
      for (int n = 0; n < 4; ++n) {
        int col = j0 + wc * 64 + n * 16 + (lane & 15);
        float* cp = base + (size_t)row * NCOUT + col;
#pragma unroll
        for (int r = 0; r < 4; ++r) cp[(size_t)r * NCOUT] = acc[m][n][r];
      }
    }
  }
}

// ---------------- persistent DAG Cholesky, 64x64 tiles, MERGED SPINE ----------------
// Block (k,k-1) handles BOTH the spine off-diag AND diag(k): trailing updates
// for P(k,k-1) (At x Bt) and Q(k,k) (At x At, same staged tile), ONE chain
// observe (merged k-1's combined publish covers C(k-1,k-2) and iA(k-1)),
// trsm, local Q -= C C^T, factor64, ONE combined publish {C flag, iA flag}.
// Registers: P 16 + Q 16 + C 16 floats -> no spill. Pure-diag blocks k>=1
// exit immediately. All other code paths identical to the proven R2 kernel.

// shared 64x64 factor+inverse; publishes iA + flag(s) (flag2 optional).
static __device__ __forceinline__ void factor64(
    float acc[4][4], float (&At)[64][68], float (&Bt)[64][68],
    int tid, int lane, int w, int tx, int ty,
    float* iA64q, float* logdq, int* flagq, int* flagq2) {
  __syncthreads();  // prior LDS readers done before At overwrite
#pragma unroll
  for (int r = 0; r < 4; ++r)
#pragma unroll
    for (int e = 0; e < 4; ++e) At[ty * 4 + r][tx * 4 + e] = acc[r][e];
  {
    int rr = tid >> 2, cb2 = (tid & 3) * 16;
#pragma unroll
    for (int m = 0; m < 16; ++m) Bt[rr][cb2 + m] = (rr == cb2 + m) ? 1.f : 0.f;
  }
  __syncthreads();
  float diagv = 1.f;
  for (int p = 0; p < 8; ++p) {
    int c0 = p * 8;
    if (w == 0) {
      // factor 8-col panel + forward-subst the 8 inverse rows
      float pa[8], xb[8];
#pragma unroll
      for (int e = 0; e < 8; ++e) {
        pa[e] = At[lane][c0 + e];
        xb[e] = Bt[c0 + e][lane];
      }
#pragma unroll
      for (int j = 0; j < 8; ++j) {
        float dj = rdlane(pa[j], c0 + j);
        float r0 = __builtin_amdgcn_rsqf(dj);
        r0 = r0 * (1.5f - 0.5f * dj * r0 * r0);  // one Newton step
        pa[j] *= r0;
        float xj = xb[j] * r0;
        xb[j] = xj;
        if (lane == c0 + j) diagv = dj * r0;
#pragma unroll
        for (int e = j + 1; e < 8; ++e) {
          float sv = rdlane(pa[j], c0 + e);
          pa[e] = fmaf(-pa[j], sv, pa[e]);
          xb[e] = fmaf(-sv, xj, xb[e]);
        }
      }
#pragma unroll
      for (int e = 0; e < 8; ++e) {
        At[lane][c0 + e] = pa[e];
        Bt[c0 + e][lane] = xb[e];
      }
    }
    __syncthreads();
    if (p < 7) {
      float La[8], Xp[8];
#pragma unroll
      for (int e = 0; e < 8; ++e) {
        La[e] = At[lane][c0 + e];
        Xp[e] = Bt[c0 + e][lane];
      }
      for (int c = c0 + 8 + w; c < 64; c += 4) {
        float Lc[8];
#pragma unroll
        for (int e = 0; e < 8; ++e) Lc[e] = At[c][c0 + e];  // wave-uniform bcast
        float v = At[lane][c], vb = Bt[c][lane];
#pragma unroll
        for (int e = 0; e < 8; ++e) {
          v = fmaf(-La[e], Lc[e], v);
          vb = fmaf(-Lc[e], Xp[e], vb);
        }
        At[lane][c] = v;
        Bt[c][lane] = vb;
      }
      __syncthreads();
    }
  }
  if (w == 0) logdq[lane] = logf(diagv);
  {
    float* q = iA64q;
    int rr = tid >> 2, cb2 = (tid & 3) * 16;
#pragma unroll
    for (int m = 0; m < 4; ++m)
      *(float4*)(q + rr * 64 + cb2 + m * 4) = *(const float4*)&Bt[rr][cb2 + m * 4];
  }
  __threadfence();
  __syncthreads();
  if (tid == 0) {
    __hip_atomic_store(flagq, 1, __ATOMIC_RELEASE, __HIP_MEMORY_SCOPE_AGENT);
    if (flagq2)
      __hip_atomic_store(flagq2, 1, __ATOMIC_RELEASE, __HIP_MEMORY_SCOPE_AGENT);
  }
}

__global__ __launch_bounds__(256, 3) void k_chol_dag(
    float* __restrict__ L, const float* __restrict__ Lp2,
    float* __restrict__ iA64, float* __restrict__ logd,
    int* __restrict__ flags) {
  int t0 = blockIdx.x, s = blockIdx.y;
  int bi = 0;
  while ((bi + 1) * (bi + 2) / 2 <= t0) ++bi;
  int bj = t0 - bi * (bi + 1) / 2;
  if (bi == bj && bi > 0) return;  // handled by merged spine (bi, bi-1)
  bool spine = (bj == bi - 1);
  int ib = bi * 64, jb = bj * 64;
  float* Ls = L + (size_t)s * D2;
  const float* Ps = Lp2 + (size_t)s * D2;
  int* fc = flags + s * 324;

  __shared__ float At[64][68];
  __shared__ float Bt[64][68];
  int tid = threadIdx.x, tx = tid & 15, ty = tid >> 4;
  int lane = tid & 63, w = tid >> 6;

  // load P acc = partial0 + partial1 at (bi,bj)  (+I if this is diag(0))
  float acc[4][4];
#pragma unroll
  for (int r = 0; r < 4; ++r) {
    size_t idx = (size_t)(ib + ty * 4 + r) * ND + jb + tx * 4;
    float4 v = *(const float4*)(Ls + idx);
    float4 v2 = *(const float4*)(Ps + idx);
    acc[r][0] = v.x + v2.x; acc[r][1] = v.y + v2.y;
    acc[r][2] = v.z + v2.z; acc[r][3] = v.w + v2.w;
  }
  if (bi == 0 && bj == 0) {
#pragma unroll
    for (int r = 0; r < 4; ++r)
#pragma unroll
      for (int e = 0; e < 4; ++e)
        if (ty * 4 + r == tx * 4 + e) acc[r][e] += 1.f;
  }
  // spine: also load Q acc = partial diag (bi,bi) + I
  float qcc[4][4];
  if (spine) {
#pragma unroll
    for (int r = 0; r < 4; ++r) {
      size_t idx = (size_t)(ib + ty * 4 + r) * ND + ib + tx * 4;
      float4 v = *(const float4*)(Ls + idx);
      float4 v2 = *(const float4*)(Ps + idx);
      qcc[r][0] = v.x + v2.x; qcc[r][1] = v.y + v2.y;
      qcc[r][2] = v.z + v2.z; qcc[r][3] = v.w + v2.w;
    }
#pragma unroll
    for (int r = 0; r < 4; ++r)
#pragma unroll
      for (int e = 0; e < 4; ++e)
        if (ty * 4 + r == tx * 4 + e) qcc[r][e] += 1.f;
  }

  // trailing updates k < bj: P -= L(bi,k) L(bj,k)^T; spine: Q -= L(bi,k) L(bi,k)^T
  for (int k = 0; k < bj; ++k) {
    if (tid == 0) {
      while (__hip_atomic_load(&fc[bi * 18 + k], __ATOMIC_RELAXED,
                               __HIP_MEMORY_SCOPE_AGENT) == 0)
        __builtin_amdgcn_s_sleep(2);
      while (__hip_atomic_load(&fc[bj * 18 + k], __ATOMIC_RELAXED,
                               __HIP_MEMORY_SCOPE_AGENT) == 0)
        __builtin_amdgcn_s_sleep(2);
      (void)__hip_atomic_load(&fc[bj * 18 + k], __ATOMIC_ACQUIRE,
                              __HIP_MEMORY_SCOPE_AGENT);
    }
    __syncthreads();
    int kb = k * 64;
    {
      int a2 = tid >> 2, km = (tid & 3) * 4;
#pragma unroll
      for (int m = 0; m < 4; ++m) {
        float4 v = *(const float4*)(Ls + (size_t)(ib + a2) * ND + kb + km + m * 16);
        At[km + m * 16 + 0][a2] = v.x;
        At[km + m * 16 + 1][a2] = v.y;
        At[km + m * 16 + 2][a2] = v.z;
        At[km + m * 16 + 3][a2] = v.w;
        float4 u4 = *(const float4*)(Ls + (size_t)(jb + a2) * ND + kb + km + m * 16);
        Bt[km + m * 16 + 0][a2] = u4.x;
        Bt[km + m * 16 + 1][a2] = u4.y;
        Bt[km + m * 16 + 2][a2] = u4.z;
        Bt[km + m * 16 + 3][a2] = u4.w;
      }
    }
    __syncthreads();
    if (spine) {
#pragma unroll
      for (int kc = 0; kc < 64; ++kc) {
        float4 a4 = *(const float4*)&At[kc][ty * 4];
        float4 b4 = *(const float4*)&Bt[kc][tx * 4];
        float4 c4v = *(const float4*)&At[kc][tx * 4];
        float ar[4] = {a4.x, a4.y, a4.z, a4.w};
        float br[4] = {b4.x, b4.y, b4.z, b4.w};
        float cr[4] = {c4v.x, c4v.y, c4v.z, c4v.w};
#pragma unroll
        for (int r = 0; r < 4; ++r)
#pragma unroll
          for (int e = 0; e < 4; ++e) {
            acc[r][e] = fmaf(-ar[r], br[e], acc[r][e]);
            qcc[r][e] = fmaf(-ar[r], cr[e], qcc[r][e]);
          }
      }
    } else {
#pragma unroll
      for (int kc = 0; kc < 64; ++kc) {
        float4 a4 = *(const float4*)&At[kc][ty * 4];
        float4 b4 = *(const float4*)&Bt[kc][tx * 4];
        float ar[4] = {a4.x, a4.y, a4.z, a4.w};
        float br[4] = {b4.x, b4.y, b4.z, b4.w};
#pragma unroll
        for (int r = 0; r < 4; ++r)
#pragma unroll
          for (int e = 0; e < 4; ++e) acc[r][e] = fmaf(-ar[r], br[e], acc[r][e]);
      }
    }
    __syncthreads();
  }

  if (bi == 0 && bj == 0) {
    // first diag: factor directly, publish iA(0)
    factor64(acc, At, Bt, tid, lane, w, tx, ty,
             iA64 + (size_t)(s * 18) * 4096, logd + (size_t)s * ND,
             &fc[0], nullptr);
    return;
  }

  // ---- trsm: C = P @ iA(bj)^T ----
#pragma unroll
  for (int r = 0; r < 4; ++r)
#pragma unroll
    for (int e = 0; e < 4; ++e) At[tx * 4 + e][ty * 4 + r] = acc[r][e];
  waitflag0(&fc[bj * 18 + bj], tid);
  {
    const float* q = iA64 + (size_t)(s * 18 + bj) * 4096;
    int a2 = tid >> 2, km = (tid & 3) * 4;
#pragma unroll
    for (int m = 0; m < 4; ++m) {
      float4 v = *(const float4*)(q + a2 * 64 + km + m * 16);
      Bt[km + m * 16 + 0][a2] = v.x;
      Bt[km + m * 16 + 1][a2] = v.y;
      Bt[km + m * 16 + 2][a2] = v.z;
      Bt[km + m * 16 + 3][a2] = v.w;
    }
  }
  __syncthreads();
  float c2[4][4] = {};
#pragma unroll
  for (int kc = 0; kc < 64; ++kc) {
    float4 a4 = *(const float4*)&At[kc][ty * 4];
    float4 b4 = *(const float4*)&Bt[kc][tx * 4];
    float ar[4] = {a4.x, a4.y, a4.z, a4.w};
    float br[4] = {b4.x, b4.y, b4.z, b4.w};
#pragma unroll
    for (int r = 0; r < 4; ++r)
#pragma unroll
      for (int e = 0; e < 4; ++e) c2[r][e] = fmaf(ar[r], br[e], c2[r][e]);
  }
#pragma unroll
  for (int r = 0; r < 4; ++r) {
    float4 v = {c2[r][0], c2[r][1], c2[r][2], c2[r][3]};
    *(float4*)(Ls + (size_t)(ib + ty * 4 + r) * ND + jb + tx * 4) = v;
  }

  if (!spine) {
    // standard off-diag: publish C
    __threadfence();
    __syncthreads();
    if (tid == 0)
      __hip_atomic_store(&fc[bi * 18 + bj], 1, __ATOMIC_RELEASE,
                         __HIP_MEMORY_SCOPE_AGENT);
  } else {
    // ---- merged spine: Q -= C C^T, factor, combined publish {iA, C} ----
    __syncthreads();  // trsm GEMM reads of At done before overwrite
#pragma unroll
    for (int r = 0; r < 4; ++r)
#pragma unroll
      for (int e = 0; e < 4; ++e) At[tx * 4 + e][ty * 4 + r] = c2[r][e];
    __syncthreads();
#pragma unroll
    for (int kc = 0; kc < 64; ++kc) {
      float4 a4 = *(const float4*)&At[kc][ty * 4];
      float4 b4 = *(const float4*)&At[kc][tx * 4];
      float ar[4] = {a4.x, a4.y, a4.z, a4.w};
      float br[4] = {b4.x, b4.y, b4.z, b4.w};
#pragma unroll
      for (int r = 0; r < 4; ++r)
#pragma unroll
        for (int e = 0; e < 4; ++e) qcc[r][e] = fmaf(-ar[r], br[e], qcc[r][e]);
    }
    factor64(qcc, At, Bt, tid, lane, w, tx, ty,
             iA64 + (size_t)(s * 18 + bi) * 4096, logd + (size_t)s * ND + ib,
             &fc[bi * 18 + bi], &fc[bi * 18 + bj]);
  }
}

// ---------------- invert 128x128 diag blocks ----------------
// 64x64 diag inverses are already in iA64 (from k_chol_dag) — just load them.
__global__ __launch_bounds__(256) void k_invd128(const float* __restrict__ L,
                                                 const float* __restrict__ iA64,
                                                 float* __restrict__ iD) {
  int q = blockIdx.x, s = blockIdx.y;
  int tid = threadIdx.x;
  const float* Ls = L + (size_t)s * D2;
  float* out = iD + ((size_t)(s * 9 + q)) * 16384;
  int b0 = q * 128;
  __shared__ float inv0[64][68];
  __shared__ float invCt[64][68];
  __shared__ float Bt[64][68];
  __shared__ float Tl[64][68];

  {
    const float* iA0 = iA64 + (size_t)(s * 18 + 2 * q) * 4096;
    const float* iA1 = iA0 + 4096;
    int i = tid >> 2, c4 = (tid & 3) * 16;
#pragma unroll
    for (int m = 0; m < 4; ++m) {
      float4 v0 = *(const float4*)(iA0 + i * 64 + c4 + m * 4);
      *(float4*)&inv0[i][c4 + m * 4] = v0;
      float4 v1 = *(const float4*)(iA1 + i * 64 + c4 + m * 4);
      invCt[c4 + m * 4 + 0][i] = v1.x;
      invCt[c4 + m * 4 + 1][i] = v1.y;
      invCt[c4 + m * 4 + 2][i] = v1.z;
      invCt[c4 + m * 4 + 3][i] = v1.w;
    }
    // B = L(rows 64..127, cols 0..63), stored transposed: Bt[k][i]
    const float* src = Ls + (size_t)(b0 + 64 + i) * ND + b0 + c4;
#pragma unroll
    for (int m = 0; m < 4; ++m) {
      float4 v = *(const float4*)(src + m * 4);
      Bt[c4 + m * 4 + 0][i] = v.x;
      Bt[c4 + m * 4 + 1][i] = v.y;
      Bt[c4 + m * 4 + 2][i] = v.z;
      Bt[c4 + m * 4 + 3][i] = v.w;
    }
  }
  __syncthreads();

  int tx = tid & 15, ty = tid >> 4;
  float acc[4][4] = {};
#pragma unroll
  for (int k = 0; k < 64; ++k) {
    float a4[4], b4[4];
#pragma unroll
    for (int e = 0; e < 4; ++e) { a4[e] = Bt[k][ty * 4 + e]; b4[e] = inv0[k][tx * 4 + e]; }
#pragma unroll
    for (int r = 0; r < 4; ++r)
#pragma unroll
      for (int e = 0; e < 4; ++e) acc[r][e] = fmaf(a4[r], b4[e], acc[r][e]);
  }
#pragma unroll
  for (int r = 0; r < 4; ++r)
#pragma unroll
    for (int e = 0; e < 4; ++e) Tl[ty * 4 + r][tx * 4 + e] = acc[r][e];
  __syncthreads();
  float acc2[4][4] = {};
#pragma unroll
  for (int k = 0; k < 64; ++k) {
    float a4[4], b4[4];
#pragma unroll
    for (int e = 0; e < 4; ++e) { a4[e] = invCt[k][ty * 4 + e]; b4[e] = Tl[k][tx * 4 + e]; }
#pragma unroll
    for (int r = 0; r < 4; ++r)
#pragma unroll
      for (int e = 0; e < 4; ++e) acc2[r][e] = fmaf(a4[r], b4[e], acc2[r][e]);
  }
  {
    int rrow = tid >> 2, cc = (tid & 3) * 32;
    float* o = out + rrow * 128 + cc;
    if (cc < 64) {
#pragma unroll
      for (int m = 0; m < 8; ++m) {
        float4 v = {inv0[rrow][cc + m * 4 + 0], inv0[rrow][cc + m * 4 + 1],
                    inv0[rrow][cc + m * 4 + 2], inv0[rrow][cc + m * 4 + 3]};
        *(float4*)(o + m * 4) = v;
      }
    } else {
      float4 z = {0.f, 0.f, 0.f, 0.f};
#pragma unroll
      for (int m = 0; m < 8; ++m) *(float4*)(o + m * 4) = z;
    }
  }
#pragma unroll
  for (int r = 0; r < 4; ++r) {
    float4 v = {-acc2[r][0], -acc2[r][1], -acc2[r][2], -acc2[r][3]};
    *(float4*)(out + (size_t)(64 + ty * 4 + r) * 128 + tx * 4) = v;
  }
  {
    int i = tid >> 2, jc = (tid & 3) * 16;
#pragma unroll
    for (int m = 0; m < 4; ++m) {
      float4 v = {invCt[jc + m * 4 + 0][i], invCt[jc + m * 4 + 1][i],
                  invCt[jc + m * 4 + 2][i], invCt[jc + m * 4 + 3][i]};
      *(float4*)(out + (size_t)(64 + i) * 128 + 64 + jc + m * 4) = v;
    }
  }
}

// ---------------- merged persistent fwd+bwd solve (fused addz/writewm) ----------------
__global__ __launch_bounds__(256) void k_solve2(
    const float* __restrict__ L, const float* __restrict__ iD,
    const float* __restrict__ B1, const float* __restrict__ B2,
    const float* __restrict__ Z, float* __restrict__ Xf, float* __restrict__ Xb,
    float* __restrict__ Wm, float* __restrict__ pp, int* __restrict__ flags) {
  int r = blockIdx.x, ct = blockIdx.y, s = blockIdx.z;
  int rb = r * 128, cb = ct * 64;
  const float* Ls = L + (size_t)s * D2;
  const float* Dq = iD + ((size_t)(s * 9 + r)) * 16384;
  float* Xfs = Xf + (size_t)s * ND * NCOUT;
  float* Xbs = Xb + (size_t)s * ND * NCOUT;
  int fbf = 1296 + (s * 4 + ct) * 9;
  int fbb = 1440 + (s * 4 + ct) * 9;

  __shared__ float sA[32][132];
  __shared__ float sB[32][68];
  __shared__ float red[8];
  int tid = threadIdx.x, tx = tid & 15, ty = tid >> 4;
  int wave = tid >> 6, lane = tid & 63;

  // ======== forward ========
  float acc[8][4];
#pragma unroll
  for (int ii = 0; ii < 8; ++ii) {
    size_t idx = (size_t)s * ND * NCOUT + (size_t)(rb + ty * 8 + ii) * NCOUT + cb + tx * 4;
    float4 v = *(const float4*)(B1 + idx);
    float4 v2 = *(const float4*)(B2 + idx);
    acc[ii][0] = v.x + v2.x; acc[ii][1] = v.y + v2.y;
    acc[ii][2] = v.z + v2.z; acc[ii][3] = v.w + v2.w;
  }
  for (int q = 0; q < r; ++q) {
    waitflag0(&flags[fbf + q], tid);
    int qb = q * 128;
    for (int kk = 0; kk < 4; ++kk) {
      __syncthreads();
      {
        int i = tid >> 1, kb = (tid & 1) * 16;
        const float* src = Ls + (size_t)(rb + i) * ND + qb + kk * 32 + kb;
#pragma unroll
        for (int m = 0; m < 4; ++m) {
          float4 v = *(const float4*)(src + m * 4);
          sA[kb + m * 4 + 0][i] = v.x;
          sA[kb + m * 4 + 1][i] = v.y;
          sA[kb + m * 4 + 2][i] = v.z;
          sA[kb + m * 4 + 3][i] = v.w;
        }
      }
      {
        int k = tid >> 3, jb2 = (tid & 7) * 8;
        const float* src = Xfs + (size_t)(qb + kk * 32 + k) * NCOUT + cb + jb2;
        float4 v0 = *(const float4*)src;
        float4 v1 = *(const float4*)(src + 4);
        *(float4*)&sB[k][jb2] = v0;
        *(float4*)&sB[k][jb2 + 4] = v1;
      }
      __syncthreads();
#pragma unroll
      for (int k = 0; k < 32; ++k) {
        float4 a0 = *(const float4*)&sA[k][ty * 8];
        float4 a1 = *(const float4*)&sA[k][ty * 8 + 4];
        float4 b0 = *(const float4*)&sB[k][tx * 4];
        float a[8] = {a0.x, a0.y, a0.z, a0.w, a1.x, a1.y, a1.z, a1.w};
        float b[4] = {b0.x, b0.y, b0.z, b0.w};
#pragma unroll
        for (int ii = 0; ii < 8; ++ii)
#pragma unroll
          for (int j = 0; j < 4; ++j) acc[ii][j] = fmaf(-a[ii], b[j], acc[ii][j]);
      }
    }
  }
  float acc2[8][4] = {};
  for (int kk = 0; kk < 4; ++kk) {
    __syncthreads();
    if ((ty >> 2) == kk) {
      int kloc = ty * 8 - kk * 32;
#pragma unroll
      for (int ii = 0; ii < 8; ++ii) {
        float4 v = {acc[ii][0], acc[ii][1], acc[ii][2], acc[ii][3]};
        *(float4*)&sB[kloc + ii][tx * 4] = v;
      }
    }
    {
      int i = tid >> 1, kb = (tid & 1) * 16;
      const float* src = Dq + (size_t)i * 128 + kk * 32 + kb;
#pragma unroll
      for (int m = 0; m < 4; ++m) {
        float4 v = *(const float4*)(src + m * 4);
        sA[kb + m * 4 + 0][i] = v.x;
        sA[kb + m * 4 + 1][i] = v.y;
        sA[kb + m * 4 + 2][i] = v.z;
        sA[kb + m * 4 + 3][i] = v.w;
      }
    }
    __syncthreads();
#pragma unroll
    for (int k = 0; k < 32; ++k) {
      float4 a0 = *(const float4*)&sA[k][ty * 8];
      float4 a1 = *(const float4*)&sA[k][ty * 8 + 4];
      float4 b0 = *(const float4*)&sB[k][tx * 4];
      float a[8] = {a0.x, a0.y, a0.z, a0.w, a1.x, a1.y, a1.z, a1.w};
      float b[4] = {b0.x, b0.y, b0.z, b0.w};
#pragma unroll
      for (int ii = 0; ii < 8; ++ii)
#pragma unroll
        for (int j = 0; j < 4; ++j) acc2[ii][j] = fmaf(a[ii], b[j], acc2[ii][j]);
    }
  }
#pragma unroll
  for (int ii = 0; ii < 8; ++ii) {
    float4 v = {acc2[ii][0], acc2[ii][1], acc2[ii][2], acc2[ii][3]};
    *(float4*)(Xfs + (size_t)(rb + ty * 8 + ii) * NCOUT + cb + tx * 4) = v;
  }
  __threadfence();
  __syncthreads();
  if (tid == 0)
    __hip_atomic_store(&flags[fbf + r], 1, __ATOMIC_RELEASE,
                       __HIP_MEMORY_SCOPE_AGENT);

  // ======== backward (init from fwd result in registers) ========
#pragma unroll
  for (int ii = 0; ii < 8; ++ii)
#pragma unroll
    for (int j = 0; j < 4; ++j) acc[ii][j] = acc2[ii][j];

  float zp = 0.f;
  for (int kk = 0; kk < 4; ++kk) {
    __syncthreads();
    {
      int c = tid >> 2, d8 = (tid & 3) * 8;
      const float* src = Z + ((size_t)(s * NCOUT) + cb + c) * ND + rb + kk * 32 + d8;
      float4 v0 = *(const float4*)src;
      float4 v1 = *(const float4*)(src + 4);
      sA[d8 + 0][c] = v0.x; sA[d8 + 1][c] = v0.y; sA[d8 + 2][c] = v0.z; sA[d8 + 3][c] = v0.w;
      sA[d8 + 4][c] = v1.x; sA[d8 + 5][c] = v1.y; sA[d8 + 6][c] = v1.z; sA[d8 + 7][c] = v1.w;
      zp += v0.x * v0.x + v0.y * v0.y + v0.z * v0.z + v0.w * v0.w;
      zp += v1.x * v1.x + v1.y * v1.y + v1.z * v1.z + v1.w * v1.w;
    }
    __syncthreads();
    if ((ty >> 2) == kk) {
      int kloc = ty * 8 - kk * 32;
#pragma unroll
      for (int ii = 0; ii < 8; ++ii) {
        float4 v = *(const float4*)&sA[kloc + ii][tx * 4];
        acc[ii][0] += v.x; acc[ii][1] += v.y; acc[ii][2] += v.z; acc[ii][3] += v.w;
      }
    }
  }
#pragma unroll
  for (int m2 = 32; m2 >= 1; m2 >>= 1) zp += __shfl_xor(zp, m2, 64);
  if (lane == 0) red[wave] = zp;
  __syncthreads();
  if (tid == 0) atomicAdd(pp + s, red[0] + red[1] + red[2] + red[3]);

  for (int q = 8; q > r; --q) {
    waitflag0(&flags[fbb + q], tid);
    int qb = q * 128;
    for (int kk = 0; kk < 4; ++kk) {
      __syncthreads();
      {
        int k = tid >> 3, ib2 = (tid & 7) * 16;
        const float* src = Ls + (size_t)(qb + kk * 32 + k) * ND + rb + ib2;
#pragma unroll
        for (int m = 0; m < 4; ++m)
          *(float4*)&sA[k][ib2 + m * 4] = *(const float4*)(src + m * 4);
      }
      {
        int k = tid >> 3, jb2 = (tid & 7) * 8;
        const float* src = Xbs + (size_t)(qb + kk * 32 + k) * NCOUT + cb + jb2;
        float4 v0 = *(const float4*)src;
        float4 v1 = *(const float4*)(src + 4);
        *(float4*)&sB[k][jb2] = v0;
        *(float4*)&sB[k][jb2 + 4] = v1;
      }
      __syncthreads();
#pragma unroll
      for (int k = 0; k < 32; ++k) {
        float4 a0 = *(const float4*)&sA[k][ty * 8];
        float4 a1 = *(const float4*)&sA[k][ty * 8 + 4];
        float4 b0 = *(const float4*)&sB[k][tx * 4];
        float a[8] = {a0.x, a0.y, a0.z, a0.w, a1.x, a1.y, a1.z, a1.w};
        float b[4] = {b0.x, b0.y, b0.z, b0.w};
#pragma unroll
        for (int ii = 0; ii < 8; ++ii)
#pragma unroll
          for (int j = 0; j < 4; ++j) acc[ii][j] = fmaf(-a[ii], b[j], acc[ii][j]);
      }
    }
  }
#pragma unroll
  for (int ii = 0; ii < 8; ++ii)
#pragma unroll
    for (int j = 0; j < 4; ++j) acc2[ii][j] = 0.f;
  for (int kk = 0; kk < 4; ++kk) {
    __syncthreads();
    if ((ty >> 2) == kk) {
      int kloc = ty * 8 - kk * 32;
#pragma unroll
      for (int ii = 0; ii < 8; ++ii) {
        float4 v = {acc[ii][0], acc[ii][1], acc[ii][2], acc[ii][3]};
        *(float4*)&sB[kloc + ii][tx * 4] = v;
      }
    }
    {
      int k = tid >> 3, ib2 = (tid & 7) * 16;
      const float* src = Dq + (size_t)(kk * 32 + k) * 128 + ib2;
#pragma unroll
      for (int m = 0; m < 4; ++m)
        *(float4*)&sA[k][ib2 + m * 4] = *(const float4*)(src + m * 4);
    }
    __syncthreads();
#pragma unroll
    for (int k = 0; k < 32; ++k) {
      float4 a0 = *(const float4*)&sA[k][ty * 8];
      float4 a1 = *(const float4*)&sA[k][ty * 8 + 4];
      float4 b0 = *(const float4*)&sB[k][tx * 4];
      float a[8] = {a0.x, a0.y, a0.z, a0.w, a1.x, a1.y, a1.z, a1.w};
      float b[4] = {b0.x, b0.y, b0.z, b0.w};
#pragma unroll
      for (int ii = 0; ii < 8; ++ii)
#pragma unroll
        for (int j = 0; j < 4; ++j) acc2[ii][j] = fmaf(a[ii], b[j], acc2[ii][j]);
    }
  }
#pragma unroll
  for (int ii = 0; ii < 8; ++ii) {
    float4 v = {acc2[ii][0], acc2[ii][1], acc2[ii][2], acc2[ii][3]};
    *(float4*)(Xbs + (size_t)(rb + ty * 8 + ii) * NCOUT + cb + tx * 4) = v;
  }
  __threadfence();
  __syncthreads();
  if (tid == 0)
    __hip_atomic_store(&flags[fbb + r], 1, __ATOMIC_RELEASE,
                       __HIP_MEMORY_SCOPE_AGENT);
  float wp = 0.f;
#pragma unroll
  for (int ii = 0; ii < 8; ++ii)
#pragma unroll
    for (int j = 0; j < 4; ++j) wp += acc2[ii][j] * acc2[ii][j];
#pragma unroll
  for (int m2 = 32; m2 >= 1; m2 >>= 1) wp += __shfl_xor(wp, m2, 64);
  __syncthreads();
  if (lane == 0) red[wave] = wp;
  __syncthreads();
  if (tid == 0) atomicAdd(pp + 4 + s, red[0] + red[1] + red[2] + red[3]);
  for (int kk = 0; kk < 4; ++kk) {
    __syncthreads();
    if ((ty >> 2) == kk) {
      int kloc = ty * 8 - kk * 32;
#pragma unroll
      for (int ii = 0; ii < 8; ++ii) {
        float4 v = {acc2[ii][0], acc2[ii][1], acc2[ii][2], acc2[ii][3]};
        *(float4*)&sB[kloc + ii][tx * 4] = v;
      }
    }
    __syncthreads();
    {
      int c = tid >> 2, d8 = (tid & 3) * 8;
      float t0 = sB[d8 + 0][c], t1 = sB[d8 + 1][c], t2 = sB[d8 + 2][c], t3 = sB[d8 + 3][c];
      float t4 = sB[d8 + 4][c], t5 = sB[d8 + 5][c], t6 = sB[d8 + 6][c], t7 = sB[d8 + 7][c];
      float* dst = Wm + ((size_t)(s * NCOUT) + cb + c) * ND + rb + kk * 32 + d8;
      float4 w0 = {t0, t1, t2, t3}, w1 = {t4, t5, t6, t7};
      *(float4*)dst = w0;
      *(float4*)(dst + 4) = w1;
    }
  }
}

__global__ __launch_bounds__(256) void k_finalize(const float* __restrict__ logd,
                                                  const float* __restrict__ pp,
                                                  float* __restrict__ out) {
  int s = blockIdx.x, tid = threadIdx.x;
  __shared__ float r0[256];
  float l = 0.f;
  for (int i = tid; i < ND; i += 256) l += logd[s * ND + i];
  r0[tid] = l;
  __syncthreads();
  for (int off = 128; off; off >>= 1) {
    if (tid < off) r0[tid] += r0[tid + off];
    __syncthreads();
  }
  if (tid == 0) {
    float logdet = 2.0f * r0[0];
    out[s] = 0.5f * (pp[s] - pp[4 + s]) - 128.0f * logdet;
  }
}

// ---------------- launcher ----------------
extern "C" void kernel_launch(void* const* d_in, const int* in_sizes, int n_in,
                              void* d_out, int out_size, void* d_ws, size_t ws_size,
                              hipStream_t stream) {
  const float* X = (const float*)d_in[0];
  const float* u = (const float*)d_in[1];
  const float* lp = (const float*)d_in[2];
  const float* Z = (const float*)d_in[3];
  float* out = (float*)d_out;

  float* ws = (float*)d_ws;
  float* sp    = ws;                                    // 64
  float* invd  = sp + 64;                               // 4608 (unused, layout kept)
  float* logd  = invd + (size_t)NS * ND;                // 4608
  float* pp    = logd + (size_t)NS * ND;                // 64
  int*   flags = (int*)(pp + 64);                       // 2048 ints (1584 used)
  float* iD    = (float*)(flags + 2048);                // 4*9*16384
  float* iA64  = iD + (size_t)NS * 9 * 16384;           // 4*18*4096
  float* Xf    = iA64 + (size_t)NS * 18 * 4096;         // 4*1152*256
  float* Xb    = Xf + (size_t)NS * ND * NCOUT;          // 4*1152*256
  float* prec  = Xb + (size_t)NS * ND * NCOUT;          // 4*1152*1152
  float* prec2 = prec + (size_t)NS * D2;                // 4*1152*1152
  float* XLY   = prec2 + (size_t)NS * D2;               // 4*1152*256
  float* XLY2  = XLY + (size_t)NS * ND * NCOUT;         // 4*1152*256
  unsigned short* Phi = (unsigned short*)(XLY2 + (size_t)NS * ND * NCOUT);
  unsigned short* Plo = Phi + (size_t)NS * ND * NK;
  unsigned short* Yhi = Plo + (size_t)NS * ND * NK;
  unsigned short* Ylo = Yhi + (size_t)NCOUT * NK;

  hipMemsetAsync(flags, 0, 2048 * sizeof(int), stream);
  k_sqrtp<<<1, 64, 0, stream>>>(lp, sp, pp);
  k_patches<<<dim3(ND, NS), 128, 0, stream>>>(X, sp, Phi, Plo);
  k_ytt<<<NCOUT, 128, 0, stream>>>(u, sp, Yhi, Ylo);
  k_gemm_mfma<<<dim3(11, 9, NS * 2), 256, 0, stream>>>(Phi, Plo, Yhi, Ylo, prec,
                                                       prec2, XLY, XLY2);
  k_chol_dag<<<dim3(171, NS), 256, 0, stream>>>(prec, prec2, iA64, logd, flags);
  k_invd128<<<dim3(9, NS), 256, 0, stream>>>(prec, iA64, iD);
  k_solve2<<<dim3(9, 4, NS), 256, 0, stream>>>(prec, iD, XLY, XLY2, Z, Xf, Xb,
                                               out, pp, flags);
  k_finalize<<<NS, 256, 0, stream>>>(logd, pp, out + (size_t)NS * NCOUT * ND);
}